// Round 1
// baseline (1651.774 us; speedup 1.0000x reference)
//
#include <hip/hip_runtime.h>

#define E 64
#define D 50
#define SS 384
#define G4 256   // 4*E

__device__ __forceinline__ float fast_rcp(float x){ return __builtin_amdgcn_rcpf(x); }
__device__ __forceinline__ float tanh_fast(float x){
  // tanh(x) = 1 - 2/(exp(2x)+1)
  float e = __expf(2.0f*x);
  return 1.0f - 2.0f*fast_rcp(e + 1.0f);
}
__device__ __forceinline__ float sigmoid_fast(float x){
  return fast_rcp(1.0f + __expf(-x));
}
// whole-wave rotate via DPP (VALU pipe, NOT the DS pipe).
// wave_ror:1: lane i receives the value of lane (i-1)&63.
__device__ __forceinline__ float ror1(float x){
  return __int_as_float(__builtin_amdgcn_update_dpp(
      0, __float_as_int(x), 0x13C /*wave_ror:1*/, 0xF, 0xF, false));
}
__device__ __forceinline__ float rdlane(float v, int l){
  return __int_as_float(__builtin_amdgcn_readlane(__float_as_int(v), l));
}
// DPP-shifted copy with 0 for invalid source lanes (ctrl must be a literal).
#define DPP0(x, ctrl) __int_as_float(__builtin_amdgcn_update_dpp( \
    0, __float_as_int(x), ctrl, 0xF, 0xF, true))
// wave64 sum; full sum valid in lane 63 (classic row_shr + row_bcast ladder)
__device__ __forceinline__ float wave_sum64_l63(float x){
  x += DPP0(x, 0x111);  // row_shr:1
  x += DPP0(x, 0x112);  // row_shr:2
  x += DPP0(x, 0x114);  // row_shr:4
  x += DPP0(x, 0x118);  // row_shr:8
  x += DPP0(x, 0x142);  // row_bcast:15
  x += DPP0(x, 0x143);  // row_bcast:31
  return x;
}

// ---------------------------------------------------------------------------
// K0: gx[b,s,j] = bias[j] + sum_k emb[sent[b,s],k] * Wih[j,k]   (both LSTMs)
// ---------------------------------------------------------------------------
__global__ __launch_bounds__(256, 1) void gx_kernel(
  const int* __restrict__ sent1, const int* __restrict__ sent2,
  const float* __restrict__ emb,
  const float* __restrict__ Wih1, const float* __restrict__ bih1, const float* __restrict__ bhh1,
  const float* __restrict__ Wih2, const float* __restrict__ bih2, const float* __restrict__ bhh2,
  float* __restrict__ gx1, float* __restrict__ gx2)
{
  const int bb    = blockIdx.x;     // 0..511
  const int which = bb >> 8;
  const int chunk = bb & 255;
  const int j     = threadIdx.x;
  const int*   sent = which ? sent2 : sent1;
  const float* Wih  = which ? Wih2  : Wih1;
  const float* bA   = which ? bih2  : bih1;
  const float* bB   = which ? bhh2  : bhh1;
  float*       gx   = which ? gx2   : gx1;

  float wih[D];
  #pragma unroll
  for (int k=0;k<D;k+=2){
    float2 v = *(const float2*)&Wih[j*D+k];
    wih[k]=v.x; wih[k+1]=v.y;
  }
  const float bias = bA[j] + bB[j];

  __shared__ __align__(16) float xb[8][52];
  const int row0 = chunk*96;
  for (int c=0;c<12;++c){
    const int r0 = row0 + c*8;
    #pragma unroll
    for (int q=0;q<2;++q){
      int tt = j + q*256;
      if (tt < 400){
        int r = tt/50;
        int k = tt - r*50;
        int idx = sent[r0 + r];
        xb[r][k] = emb[(size_t)idx*D + k];
      }
    }
    __syncthreads();
    for (int r=0;r<8;++r){
      float a0=bias, a1=0.f;
      #pragma unroll
      for (int k=0;k<48;k+=4){
        float4 xv = *(const float4*)&xb[r][k];
        a0 += xv.x*wih[k]   + xv.y*wih[k+1];
        a1 += xv.z*wih[k+2] + xv.w*wih[k+3];
      }
      a0 += xb[r][48]*wih[48];
      a1 += xb[r][49]*wih[49];
      gx[(size_t)(r0+r)*G4 + j] = a0+a1;
    }
    __syncthreads();
  }
}

// ---------------------------------------------------------------------------
// K1: both LSTM recurrences. 64 blocks x 256 threads (4 waves).
// ONE barrier per step: h/c are register-resident in EVERY wave (redundant
// identical elementwise update from the shared gates LDS), and the gates
// buffer is double-buffered so no trailing barrier is needed.
// ---------------------------------------------------------------------------
__global__ __launch_bounds__(256, 1) void lstm_kernel(
  const float* __restrict__ gx1, const float* __restrict__ gx2,
  const float* __restrict__ Whh1, const float* __restrict__ Whh2,
  const int* __restrict__ s1_len, const int* __restrict__ s2_len,
  float* __restrict__ h1_all, float* __restrict__ out_all,
  float* __restrict__ hn_cap)
{
  const int b = blockIdx.x;
  const int j = threadIdx.x;
  const int lane = j & 63;
  const int wv = j >> 6;
  __shared__ float gates[2][256];

  float whht[64];                       // whht[i] = Whh[j][(lane-i)&63] (ror direction)
  #pragma unroll
  for (int i=0;i<32;++i){
    whht[i]    = Whh1[j*64 + ((lane-i)&63)];
    whht[i+32] = Whh1[j*64 + ((lane-i+32)&63)];
  }

  const int is_g = (wv==2);             // wave-uniform: gate 'g' uses tanh
  float c_reg=0.f, h_reg=0.f, gh=0.f, gc=0.f, hn=0.f;
  const int idx1 = s1_len[b*64+lane];
  const int idx2 = s2_len[b*64+lane];

  // ---- LSTM1 ----
  {
    const float* gx = gx1 + (size_t)b*SS*G4;
    float* hout = h1_all + (size_t)b*SS*E;
    float gx_cur = gx[j];
    float gx_n1  = gx[G4 + j];
    for (int s=0;s<SS;++s){
      int sn2 = (s+2<SS)? s+2 : SS-1;
      float gx_n2 = gx[(size_t)sn2*G4 + j];
      float hr  = h_reg;                    // h[lane]
      float hr2 = __shfl_xor(h_reg, 32);    // h[lane^32]
      float g0 = gx_cur, g1 = 0.f;
      #pragma unroll
      for (int i=0;i<32;++i){
        g0 = __builtin_fmaf(hr,  whht[i],    g0);
        g1 = __builtin_fmaf(hr2, whht[i+32], g1);
        hr = ror1(hr); hr2 = ror1(hr2);
      }
      float g = g0 + g1;
      const int p = s & 1;
      gates[p][j] = is_g ? tanh_fast(g) : sigmoid_fast(g);
      __syncthreads();
      // redundant identical update in all 4 waves (keeps h in registers)
      float gi=gates[p][lane], gf=gates[p][64+lane], gg=gates[p][128+lane], go=gates[p][192+lane];
      c_reg = gf*c_reg + gi*gg;
      h_reg = go * tanh_fast(c_reg);
      if (wv==0) hout[(size_t)s*E + lane] = h_reg;
      if (s==idx1){ gh=h_reg; gc=c_reg; }
      gx_cur = gx_n1; gx_n1 = gx_n2;
      // no second barrier: next step writes the OTHER gates buffer, and a
      // buffer is only rewritten after a barrier every wave passed post-read.
    }
  }
  // ---- LSTM2 ----
  #pragma unroll
  for (int i=0;i<32;++i){
    whht[i]    = Whh2[j*64 + ((lane-i)&63)];
    whht[i+32] = Whh2[j*64 + ((lane-i+32)&63)];
  }
  h_reg = gh; c_reg = gc;
  __syncthreads();
  {
    const float* gx = gx2 + (size_t)b*SS*G4;
    float* hout = out_all + (size_t)b*SS*E;
    float gx_cur = gx[j];
    float gx_n1  = gx[G4 + j];
    for (int s=0;s<SS;++s){
      int sn2 = (s+2<SS)? s+2 : SS-1;
      float gx_n2 = gx[(size_t)sn2*G4 + j];
      float hr  = h_reg;
      float hr2 = __shfl_xor(h_reg, 32);
      float g0 = gx_cur, g1 = 0.f;
      #pragma unroll
      for (int i=0;i<32;++i){
        g0 = __builtin_fmaf(hr,  whht[i],    g0);
        g1 = __builtin_fmaf(hr2, whht[i+32], g1);
        hr = ror1(hr); hr2 = ror1(hr2);
      }
      float g = g0 + g1;
      const int p = s & 1;
      gates[p][j] = is_g ? tanh_fast(g) : sigmoid_fast(g);
      __syncthreads();
      float gi=gates[p][lane], gf=gates[p][64+lane], gg=gates[p][128+lane], go=gates[p][192+lane];
      c_reg = gf*c_reg + gi*gg;
      h_reg = go * tanh_fast(c_reg);
      if (wv==0) hout[(size_t)s*E + lane] = h_reg;
      if (s==idx2) hn = h_reg;
      gx_cur = gx_n1; gx_n1 = gx_n2;
    }
  }
  if (wv==0) hn_cap[b*64+lane] = hn;
}

// ---------------------------------------------------------------------------
// K2: E_g[row,f] = exp( 2*(h1[row]@wy + out[row]@wh)[f] )
// (256,1): wyc+whc = 128 VGPRs must NOT spill.
// ---------------------------------------------------------------------------
__global__ __launch_bounds__(256, 1) void base_kernel(
  const float* __restrict__ h1_all, const float* __restrict__ out_all,
  const float* __restrict__ wy, const float* __restrict__ wh,
  float* __restrict__ E_g)
{
  const int t = threadIdx.x;
  const int wave = t>>6, lane = t&63;
  float wyc[E], whc[E];
  #pragma unroll
  for (int e=0;e<E;++e){ wyc[e]=wy[e*E+lane]; whc[e]=wh[e*E+lane]; }
  const int row0 = blockIdx.x*16 + wave*4;
  for (int r=0;r<4;++r){
    int row = row0 + r;
    float hv = h1_all[(size_t)row*E + lane];
    float ov = out_all[(size_t)row*E + lane];
    float a0=0,a1=0;
    #pragma unroll
    for (int e=0;e<E;++e){
      a0 += rdlane(hv,e)*wyc[e];
      a1 += rdlane(ov,e)*whc[e];
    }
    E_g[(size_t)row*E + lane] = __expf(2.0f*(a0+a1));
  }
}

// ---------------------------------------------------------------------------
// K3: attention scan. 64 blocks x 384 threads (6 waves), 384 steps.
// vs previous verified version:
//  - score loop uses pairwise fractions: w0/A + w1/B = (w0*B+w1*A)/(A*B)
//    -> 32 rcp instead of 64 per wave-step (quarter-rate trans pipe relief).
//  - 'tot' (lane-invariant wave sum of ex) via 6-instr DPP ladder instead of
//    64 adds inside the rotate-MAC loop; stored once per wave in totP[].
// ---------------------------------------------------------------------------
__global__ __launch_bounds__(384, 1) void attn_kernel(
  const float* __restrict__ h1_all, const float* __restrict__ E_all,
  const float* __restrict__ w, const float* __restrict__ wr, const float* __restrict__ wt,
  const float* __restrict__ s1_s, const int* __restrict__ s2_len,
  float* __restrict__ rn_cap)
{
  const int b = blockIdx.x;
  const int t = threadIdx.x;
  const int wv = t>>6, lane = t&63;
  const int row = wv*64 + lane;

  __shared__ float  accP[6*64];    // acc[e]-partial per wave
  __shared__ float  totP[8];       // tot per wave (lane-invariant)
  __shared__ float2 rwrtP[6*64];   // {rw-partial, rt-partial} per wave

  const float* h1b = h1_all + (size_t)b*SS*E;
  const float* Eb  = E_all  + (size_t)b*SS*E;

  // ---- preload (once) ----
  float Ee[64];                               // E row for my s-row
  #pragma unroll
  for (int k=0;k<64;k+=4){
    float4 v = *(const float4*)&Eb[(size_t)row*E + k];
    Ee[k]=v.x; Ee[k+1]=v.y; Ee[k+2]=v.z; Ee[k+3]=v.w;
  }
  float ht[64];                               // ht[i] = h[row (lane-i)&63][lane] (ror direction)
  #pragma unroll
  for (int i=0;i<32;++i){
    ht[i]    = h1b[(size_t)(wv*64 + ((lane-i)&63))*E + lane];
    ht[i+32] = h1b[(size_t)(wv*64 + ((lane-i+32)&63))*E + lane];
  }
  float WSUM = 0.f;
  for (int e=0;e<64;++e) WSUM += w[e];        // uniform -> scalar
  const float s1v = s1_s[b*SS + row];
  const int  idx2 = s2_len[b*E + lane];
  // GEMV k-chunk for this wave (rnew@wr, rnew@wt)
  const int k0  = (wv<4)? wv*11 : 44+(wv-4)*10;
  const int cnt = (wv<4)? 11 : 10;
  float wrch[11], wtch[11];
  #pragma unroll
  for (int jj=0;jj<11;++jj){
    int kk = k0 + ((jj<cnt)? jj : 0);
    wrch[jj] = wr[kk*E + lane];
    wtch[jj] = wt[kk*E + lane];
  }

  rwrtP[t] = make_float2(0.f, 0.f);   // r0 = 0 -> rw=0, rt=0
  __syncthreads();

  float rn_keep = 0.f;
  for (int s=0;s<SS;++s){
    // ---- A-pre: reduce rw/rt partials (redundant per wave, 6 b64 reads) ----
    float rwl=0.f, rtl=0.f;
    #pragma unroll
    for (int q=0;q<6;++q){ float2 v = rwrtP[q*64+lane]; rwl+=v.x; rtl+=v.y; }
    float Rl = __expf(2.0f*rwl);      // R[e=lane]

    // ---- score: sum_e w[e]/(Ee[e]*R[e]+1), pairwise-combined fractions ----
    float sc0=0.f, sc1=0.f;
    #pragma unroll
    for (int e=0;e<64;e+=4){
      float r0=rdlane(Rl,e),   r1=rdlane(Rl,e+1);
      float r2=rdlane(Rl,e+2), r3=rdlane(Rl,e+3);
      float A  = __builtin_fmaf(Ee[e],  r0, 1.f);
      float B  = __builtin_fmaf(Ee[e+1],r1, 1.f);
      float C  = __builtin_fmaf(Ee[e+2],r2, 1.f);
      float Dv = __builtin_fmaf(Ee[e+3],r3, 1.f);
      float n0 = __builtin_fmaf(w[e],   B,  w[e+1]*A);
      float n1 = __builtin_fmaf(w[e+2], Dv, w[e+3]*C);
      sc0 = __builtin_fmaf(n0, fast_rcp(A*B),  sc0);
      sc1 = __builtin_fmaf(n1, fast_rcp(C*Dv), sc1);
    }
    float sc = WSUM - 2.0f*(sc0+sc1);
    float masked = s1v*sc - (1.f - s1v)*1e12f;
    float ex = __expf(masked);        // |sc| <= sum|w| ~ 51 -> fp32 safe

    // ---- rotate-MAC: acc[e=lane] += ex[row]*h[row][lane] ----
    float exr  = ex;                  // iter i: ex[row (lane-i)&63]
    float exr2 = __shfl_xor(ex, 32);  // iter i: ex[row (lane-i+32)&63]
    float acc=0.f;
    #pragma unroll
    for (int i=0;i<32;++i){
      acc = __builtin_fmaf(exr,  ht[i],    acc);
      acc = __builtin_fmaf(exr2, ht[i+32], acc);
      exr = ror1(exr); exr2 = ror1(exr2);
    }
    accP[wv*64+lane] = acc;
    float tw = wave_sum64_l63(ex);    // lane-invariant wave total of ex
    if (lane==63) totP[wv] = tw;
    __syncthreads();

    // ---- phase C: reduce acc/tot, rnew, distributed GEMV ----
    float av=0.f;
    #pragma unroll
    for (int q=0;q<6;++q) av += accP[q*64+lane];
    float tv = ((totP[0]+totP[1])+(totP[2]+totP[3]))+(totP[4]+totP[5]);
    float rnew = __builtin_fmaf(av, fast_rcp(tv), tanh_fast(rtl));
    if (wv==0 && s==idx2) rn_keep = rnew;
    float rwp=0.f, rtp=0.f;
    #pragma unroll
    for (int jj=0;jj<11;++jj){
      if (jj<cnt){
        float rv = rdlane(rnew, k0+jj);
        rwp = __builtin_fmaf(rv, wrch[jj], rwp);
        rtp = __builtin_fmaf(rv, wtch[jj], rtp);
      }
    }
    rwrtP[wv*64+lane] = make_float2(rwp, rtp);
    __syncthreads();
  }
  if (wv==0) rn_cap[b*E + lane] = rn_keep;
}

// ---------------------------------------------------------------------------
// K4: final MLP. 64 blocks x 128 threads.
// ---------------------------------------------------------------------------
__global__ __launch_bounds__(128, 1) void final_kernel(
  const float* __restrict__ rn_cap, const float* __restrict__ hn_cap,
  const float* __restrict__ wp, const float* __restrict__ wx,
  const float* __restrict__ l1W, const float* __restrict__ l1b,
  const float* __restrict__ lW, const float* __restrict__ lb,
  float* __restrict__ out)
{
  const int b = blockIdx.x, t = threadIdx.x;
  __shared__ float rn[E], hn[E], hid1[E], hid2[128];
  if (t<E){ rn[t]=rn_cap[b*E+t]; hn[t]=hn_cap[b*E+t]; }
  __syncthreads();
  if (t<E){
    float a0=0,a1=0;
    #pragma unroll
    for (int k=0;k<E;++k){
      a0 += rn[k]*wp[k*E+t];
      a1 += hn[k]*wx[k*E+t];
    }
    hid1[t] = tanh_fast(a0+a1);
  }
  __syncthreads();
  {
    float acc = l1b[t];
    #pragma unroll
    for (int k=0;k<E;++k) acc += hid1[k]*l1W[t*E+k];
    hid2[t] = tanh_fast(acc);
  }
  __syncthreads();
  if (t<4){
    float acc = lb[t];
    #pragma unroll
    for (int k=0;k<128;++k) acc += hid2[k]*lW[t*128+k];
    out[b*4+t] = acc;
  }
}

extern "C" void kernel_launch(void* const* d_in, const int* in_sizes, int n_in,
                              void* d_out, int out_size, void* d_ws, size_t ws_size,
                              hipStream_t stream)
{
  const int*   sent1 = (const int*)  d_in[0];
  const int*   sent2 = (const int*)  d_in[1];
  const int*   s1len = (const int*)  d_in[2];
  const int*   s2len = (const int*)  d_in[3];
  const float* s1s   = (const float*)d_in[4];
  const float* emb   = (const float*)d_in[6];
  const float* Wih1  = (const float*)d_in[7];
  const float* Whh1  = (const float*)d_in[8];
  const float* bih1  = (const float*)d_in[9];
  const float* bhh1  = (const float*)d_in[10];
  const float* Wih2  = (const float*)d_in[11];
  const float* Whh2  = (const float*)d_in[12];
  const float* bih2  = (const float*)d_in[13];
  const float* bhh2  = (const float*)d_in[14];
  const float* wy    = (const float*)d_in[15];
  const float* wh    = (const float*)d_in[16];
  const float* w     = (const float*)d_in[17];
  const float* wp    = (const float*)d_in[18];
  const float* wx    = (const float*)d_in[19];
  const float* wr    = (const float*)d_in[20];
  const float* wt    = (const float*)d_in[21];
  const float* l1W   = (const float*)d_in[22];
  const float* l1b   = (const float*)d_in[23];
  const float* lW    = (const float*)d_in[24];
  const float* lb    = (const float*)d_in[25];
  float* out = (float*)d_out;

  float* ws  = (float*)d_ws;
  float* gx1 = ws;                         // 64*384*256 = 6291456 floats
  float* gx2 = gx1 + 6291456;
  float* h1  = gx2 + 6291456;              // 64*384*64 = 1572864
  float* outa= h1  + 1572864;
  float* Eg  = outa + 1572864;
  float* rnc = Eg  + 1572864;              // 4096
  float* hnc = rnc + 4096;

  hipLaunchKernelGGL(gx_kernel, dim3(512), dim3(256), 0, stream,
    sent1, sent2, emb, Wih1, bih1, bhh1, Wih2, bih2, bhh2, gx1, gx2);
  hipLaunchKernelGGL(lstm_kernel, dim3(64), dim3(256), 0, stream,
    gx1, gx2, Whh1, Whh2, s1len, s2len, h1, outa, hnc);
  hipLaunchKernelGGL(base_kernel, dim3(1536), dim3(256), 0, stream,
    h1, outa, wy, wh, Eg);
  hipLaunchKernelGGL(attn_kernel, dim3(64), dim3(384), 0, stream,
    h1, Eg, w, wr, wt, s1s, s2len, rnc);
  hipLaunchKernelGGL(final_kernel, dim3(64), dim3(128), 0, stream,
    rnc, hnc, wp, wx, l1W, l1b, lW, lb, out);
}

// Round 2
// 1326.645 us; speedup vs baseline: 1.2451x; 1.2451x over previous
//
#include <hip/hip_runtime.h>

#define E 64
#define D 50
#define SS 384
#define G4 256   // 4*E

__device__ __forceinline__ float fast_rcp(float x){ return __builtin_amdgcn_rcpf(x); }
__device__ __forceinline__ float tanh_fast(float x){
  // tanh(x) = 1 - 2/(exp(2x)+1)
  float e = __expf(2.0f*x);
  return 1.0f - 2.0f*fast_rcp(e + 1.0f);
}
__device__ __forceinline__ float sigmoid_fast(float x){
  return fast_rcp(1.0f + __expf(-x));
}
__device__ __forceinline__ float rdlane(float v, int l){
  return __int_as_float(__builtin_amdgcn_readlane(__float_as_int(v), l));
}
// DPP-shifted copy with 0 for invalid source lanes (ctrl must be a literal).
#define DPP0(x, ctrl) __int_as_float(__builtin_amdgcn_update_dpp( \
    0, __float_as_int(x), ctrl, 0xF, 0xF, true))
// wave64 sum; full sum valid in lane 63 (classic row_shr + row_bcast ladder)
__device__ __forceinline__ float wave_sum64_l63(float x){
  x += DPP0(x, 0x111);  // row_shr:1
  x += DPP0(x, 0x112);  // row_shr:2
  x += DPP0(x, 0x114);  // row_shr:4
  x += DPP0(x, 0x118);  // row_shr:8
  x += DPP0(x, 0x142);  // row_bcast:15
  x += DPP0(x, 0x143);  // row_bcast:31
  return x;
}

// ---------------------------------------------------------------------------
// K0: gx[b,s,j] = bias[j] + sum_k emb[sent[b,s],k] * Wih[j,k]   (both LSTMs)
// ---------------------------------------------------------------------------
__global__ __launch_bounds__(256, 1) void gx_kernel(
  const int* __restrict__ sent1, const int* __restrict__ sent2,
  const float* __restrict__ emb,
  const float* __restrict__ Wih1, const float* __restrict__ bih1, const float* __restrict__ bhh1,
  const float* __restrict__ Wih2, const float* __restrict__ bih2, const float* __restrict__ bhh2,
  float* __restrict__ gx1, float* __restrict__ gx2)
{
  const int bb    = blockIdx.x;     // 0..511
  const int which = bb >> 8;
  const int chunk = bb & 255;
  const int j     = threadIdx.x;
  const int*   sent = which ? sent2 : sent1;
  const float* Wih  = which ? Wih2  : Wih1;
  const float* bA   = which ? bih2  : bih1;
  const float* bB   = which ? bhh2  : bhh1;
  float*       gx   = which ? gx2   : gx1;

  float wih[D];
  #pragma unroll
  for (int k=0;k<D;k+=2){
    float2 v = *(const float2*)&Wih[j*D+k];
    wih[k]=v.x; wih[k+1]=v.y;
  }
  const float bias = bA[j] + bB[j];

  __shared__ __align__(16) float xb[8][52];
  const int row0 = chunk*96;
  for (int c=0;c<12;++c){
    const int r0 = row0 + c*8;
    #pragma unroll
    for (int q=0;q<2;++q){
      int tt = j + q*256;
      if (tt < 400){
        int r = tt/50;
        int k = tt - r*50;
        int idx = sent[r0 + r];
        xb[r][k] = emb[(size_t)idx*D + k];
      }
    }
    __syncthreads();
    for (int r=0;r<8;++r){
      float a0=bias, a1=0.f;
      #pragma unroll
      for (int k=0;k<48;k+=4){
        float4 xv = *(const float4*)&xb[r][k];
        a0 += xv.x*wih[k]   + xv.y*wih[k+1];
        a1 += xv.z*wih[k+2] + xv.w*wih[k+3];
      }
      a0 += xb[r][48]*wih[48];
      a1 += xb[r][49]*wih[49];
      gx[(size_t)(r0+r)*G4 + j] = a0+a1;
    }
    __syncthreads();
  }
}

// ---------------------------------------------------------------------------
// K1: both LSTM recurrences. 64 blocks x 256 threads (4 waves).
// One barrier per step. h lives in a per-wave LDS copy (hbuf[wv]); the MAC
// reads it via conflict-free broadcast float4 ds_reads, so Whh stays in
// NATURAL order (no rotation table, no serial DPP-ror chain) and the
// accumulator splits into 4 independent chains.
// ---------------------------------------------------------------------------
__global__ __launch_bounds__(256, 1) void lstm_kernel(
  const float* __restrict__ gx1, const float* __restrict__ gx2,
  const float* __restrict__ Whh1, const float* __restrict__ Whh2,
  const int* __restrict__ s1_len, const int* __restrict__ s2_len,
  float* __restrict__ h1_all, float* __restrict__ out_all,
  float* __restrict__ hn_cap)
{
  const int b = blockIdx.x;
  const int j = threadIdx.x;
  const int lane = j & 63;
  const int wv = j >> 6;
  __shared__ float gates[2][256];
  __shared__ __align__(16) float hbuf[4][64];   // per-wave private h copy

  float whr[64];                                // Whh row j, natural order
  #pragma unroll
  for (int k=0;k<64;k+=4){
    float4 v = *(const float4*)&Whh1[j*64+k];
    whr[k]=v.x; whr[k+1]=v.y; whr[k+2]=v.z; whr[k+3]=v.w;
  }

  const int is_g = (wv==2);             // wave-uniform: gate 'g' uses tanh
  float c_reg=0.f, h_reg=0.f, gh=0.f, gc=0.f, hn=0.f;
  const int idx1 = s1_len[b*64+lane];
  const int idx2 = s2_len[b*64+lane];
  hbuf[wv][lane] = 0.f;                 // own-wave init; intra-wave ordering only

  // ---- LSTM1 ----
  {
    const float* gx = gx1 + (size_t)b*SS*G4;
    float* hout = h1_all + (size_t)b*SS*E;
    float gx_cur = gx[j];
    float gx_n1  = gx[G4 + j];
    for (int s=0;s<SS;++s){
      int sn2 = (s+2<SS)? s+2 : SS-1;
      float gx_n2 = gx[(size_t)sn2*G4 + j];
      float g0=gx_cur, g1=0.f, g2=0.f, g3=0.f;
      #pragma unroll
      for (int k=0;k<64;k+=4){
        float4 hv = *(const float4*)&hbuf[wv][k];   // broadcast read
        g0 = __builtin_fmaf(hv.x, whr[k],   g0);
        g1 = __builtin_fmaf(hv.y, whr[k+1], g1);
        g2 = __builtin_fmaf(hv.z, whr[k+2], g2);
        g3 = __builtin_fmaf(hv.w, whr[k+3], g3);
      }
      float g = (g0+g1)+(g2+g3);
      const int p = s & 1;
      gates[p][j] = is_g ? tanh_fast(g) : sigmoid_fast(g);
      __syncthreads();
      // redundant identical update in all 4 waves (keeps h per-wave)
      float gi=gates[p][lane], gf=gates[p][64+lane], gg=gates[p][128+lane], go=gates[p][192+lane];
      c_reg = gf*c_reg + gi*gg;
      h_reg = go * tanh_fast(c_reg);
      hbuf[wv][lane] = h_reg;
      if (wv==0) hout[(size_t)s*E + lane] = h_reg;
      if (s==idx1){ gh=h_reg; gc=c_reg; }
      gx_cur = gx_n1; gx_n1 = gx_n2;
      // no second barrier: next step writes the OTHER gates buffer.
    }
  }
  // ---- LSTM2 ----
  #pragma unroll
  for (int k=0;k<64;k+=4){
    float4 v = *(const float4*)&Whh2[j*64+k];
    whr[k]=v.x; whr[k+1]=v.y; whr[k+2]=v.z; whr[k+3]=v.w;
  }
  h_reg = gh; c_reg = gc;
  hbuf[wv][lane] = gh;
  __syncthreads();
  {
    const float* gx = gx2 + (size_t)b*SS*G4;
    float* hout = out_all + (size_t)b*SS*E;
    float gx_cur = gx[j];
    float gx_n1  = gx[G4 + j];
    for (int s=0;s<SS;++s){
      int sn2 = (s+2<SS)? s+2 : SS-1;
      float gx_n2 = gx[(size_t)sn2*G4 + j];
      float g0=gx_cur, g1=0.f, g2=0.f, g3=0.f;
      #pragma unroll
      for (int k=0;k<64;k+=4){
        float4 hv = *(const float4*)&hbuf[wv][k];
        g0 = __builtin_fmaf(hv.x, whr[k],   g0);
        g1 = __builtin_fmaf(hv.y, whr[k+1], g1);
        g2 = __builtin_fmaf(hv.z, whr[k+2], g2);
        g3 = __builtin_fmaf(hv.w, whr[k+3], g3);
      }
      float g = (g0+g1)+(g2+g3);
      const int p = s & 1;
      gates[p][j] = is_g ? tanh_fast(g) : sigmoid_fast(g);
      __syncthreads();
      float gi=gates[p][lane], gf=gates[p][64+lane], gg=gates[p][128+lane], go=gates[p][192+lane];
      c_reg = gf*c_reg + gi*gg;
      h_reg = go * tanh_fast(c_reg);
      hbuf[wv][lane] = h_reg;
      if (wv==0) hout[(size_t)s*E + lane] = h_reg;
      if (s==idx2) hn = h_reg;
      gx_cur = gx_n1; gx_n1 = gx_n2;
    }
  }
  if (wv==0) hn_cap[b*64+lane] = hn;
}

// ---------------------------------------------------------------------------
// K2: E_g[row,f] = exp( 2*(h1[row]@wy + out[row]@wh)[f] )
// ---------------------------------------------------------------------------
__global__ __launch_bounds__(256, 1) void base_kernel(
  const float* __restrict__ h1_all, const float* __restrict__ out_all,
  const float* __restrict__ wy, const float* __restrict__ wh,
  float* __restrict__ E_g)
{
  const int t = threadIdx.x;
  const int wave = t>>6, lane = t&63;
  float wyc[E], whc[E];
  #pragma unroll
  for (int e=0;e<E;++e){ wyc[e]=wy[e*E+lane]; whc[e]=wh[e*E+lane]; }
  const int row0 = blockIdx.x*16 + wave*4;
  for (int r=0;r<4;++r){
    int row = row0 + r;
    float hv = h1_all[(size_t)row*E + lane];
    float ov = out_all[(size_t)row*E + lane];
    float a0=0,a1=0;
    #pragma unroll
    for (int e=0;e<E;++e){
      a0 += rdlane(hv,e)*wyc[e];
      a1 += rdlane(ov,e)*whc[e];
    }
    E_g[(size_t)row*E + lane] = __expf(2.0f*(a0+a1));
  }
}

// ---------------------------------------------------------------------------
// K3: attention scan. 64 blocks x 384 threads (6 waves), 384 steps.
// vs previous verified version:
//  - rotate-MAC replaced by intra-wave LDS broadcast: ex -> exL[wv][lane],
//    then 16 conflict-free broadcast float4 reads x 4 independent FMA chains.
//    ht[] is now in NATURAL row order (no rotation). No extra barrier (same
//    wave produces and consumes; lgkmcnt ordering suffices).
//  - R broadcast via LDS float4 (RlL[wv]) instead of 64 readlanes/step.
//  - score accumulators split into 4 independent chains.
// ---------------------------------------------------------------------------
__global__ __launch_bounds__(384, 1) void attn_kernel(
  const float* __restrict__ h1_all, const float* __restrict__ E_all,
  const float* __restrict__ w, const float* __restrict__ wr, const float* __restrict__ wt,
  const float* __restrict__ s1_s, const int* __restrict__ s2_len,
  float* __restrict__ rn_cap)
{
  const int b = blockIdx.x;
  const int t = threadIdx.x;
  const int wv = t>>6, lane = t&63;
  const int row = wv*64 + lane;

  __shared__ float  accP[6*64];                 // acc[e]-partial per wave
  __shared__ float  totP[8];                    // tot per wave
  __shared__ float2 rwrtP[6*64];                // {rw,rt}-partial per wave
  __shared__ __align__(16) float exL[6][64];    // per-wave ex broadcast
  __shared__ __align__(16) float RlL[6][64];    // per-wave R broadcast

  const float* h1b = h1_all + (size_t)b*SS*E;
  const float* Eb  = E_all  + (size_t)b*SS*E;

  // ---- preload (once) ----
  float Ee[64];                               // E row for my s-row
  #pragma unroll
  for (int k=0;k<64;k+=4){
    float4 v = *(const float4*)&Eb[(size_t)row*E + k];
    Ee[k]=v.x; Ee[k+1]=v.y; Ee[k+2]=v.z; Ee[k+3]=v.w;
  }
  float ht[64];                               // ht[i] = h[row wv*64+i][e=lane]
  #pragma unroll
  for (int i=0;i<64;++i){
    ht[i] = h1b[(size_t)(wv*64 + i)*E + lane];
  }
  float WSUM = 0.f;
  for (int e=0;e<64;++e) WSUM += w[e];        // uniform -> scalar
  const float s1v = s1_s[b*SS + row];
  const int  idx2 = s2_len[b*E + lane];
  // GEMV k-chunk for this wave (rnew@wr, rnew@wt)
  const int k0  = (wv<4)? wv*11 : 44+(wv-4)*10;
  const int cnt = (wv<4)? 11 : 10;
  float wrch[11], wtch[11];
  #pragma unroll
  for (int jj=0;jj<11;++jj){
    int kk = k0 + ((jj<cnt)? jj : 0);
    wrch[jj] = wr[kk*E + lane];
    wtch[jj] = wt[kk*E + lane];
  }

  rwrtP[t] = make_float2(0.f, 0.f);   // r0 = 0 -> rw=0, rt=0
  __syncthreads();

  float rn_keep = 0.f;
  for (int s=0;s<SS;++s){
    // ---- A-pre: reduce rw/rt partials (redundant per wave) ----
    float rwl=0.f, rtl=0.f;
    #pragma unroll
    for (int q=0;q<6;++q){ float2 v = rwrtP[q*64+lane]; rwl+=v.x; rtl+=v.y; }
    float Rl = __expf(2.0f*rwl);      // R[e=lane], identical in every wave
    RlL[wv][lane] = Rl;               // intra-wave broadcast staging

    // ---- score: sum_e w[e]/(Ee[e]*R[e]+1), pairwise fractions, 4 chains ----
    float sc0=0.f, sc1=0.f, sc2=0.f, sc3=0.f;
    #pragma unroll
    for (int e=0;e<64;e+=8){
      float4 ra = *(const float4*)&RlL[wv][e];
      float4 rb = *(const float4*)&RlL[wv][e+4];
      float A  = __builtin_fmaf(Ee[e],  ra.x, 1.f);
      float B  = __builtin_fmaf(Ee[e+1],ra.y, 1.f);
      float C  = __builtin_fmaf(Ee[e+2],ra.z, 1.f);
      float Dv = __builtin_fmaf(Ee[e+3],ra.w, 1.f);
      float n0 = __builtin_fmaf(w[e],   B,  w[e+1]*A);
      float n1 = __builtin_fmaf(w[e+2], Dv, w[e+3]*C);
      sc0 = __builtin_fmaf(n0, fast_rcp(A*B),  sc0);
      sc1 = __builtin_fmaf(n1, fast_rcp(C*Dv), sc1);
      float A2  = __builtin_fmaf(Ee[e+4], rb.x, 1.f);
      float B2  = __builtin_fmaf(Ee[e+5], rb.y, 1.f);
      float C2  = __builtin_fmaf(Ee[e+6], rb.z, 1.f);
      float D2  = __builtin_fmaf(Ee[e+7], rb.w, 1.f);
      float n2 = __builtin_fmaf(w[e+4], B2, w[e+5]*A2);
      float n3 = __builtin_fmaf(w[e+6], D2, w[e+7]*C2);
      sc2 = __builtin_fmaf(n2, fast_rcp(A2*B2), sc2);
      sc3 = __builtin_fmaf(n3, fast_rcp(C2*D2), sc3);
    }
    float sc = WSUM - 2.0f*((sc0+sc1)+(sc2+sc3));
    float masked = s1v*sc - (1.f - s1v)*1e12f;
    float ex = __expf(masked);        // |sc| <= sum|w| ~ 51 -> fp32 safe

    // ---- MAC via intra-wave LDS broadcast: acc[e=lane] += ex[row]*h[row][e] ----
    exL[wv][lane] = ex;
    float a0=0.f, a1=0.f, a2=0.f, a3=0.f;
    #pragma unroll
    for (int i=0;i<64;i+=4){
      float4 v = *(const float4*)&exL[wv][i];   // broadcast read
      a0 = __builtin_fmaf(v.x, ht[i],   a0);
      a1 = __builtin_fmaf(v.y, ht[i+1], a1);
      a2 = __builtin_fmaf(v.z, ht[i+2], a2);
      a3 = __builtin_fmaf(v.w, ht[i+3], a3);
    }
    accP[wv*64+lane] = (a0+a1)+(a2+a3);
    float tw = wave_sum64_l63(ex);    // wave total of ex
    if (lane==63) totP[wv] = tw;
    __syncthreads();

    // ---- phase C: reduce acc/tot, rnew, distributed GEMV ----
    float av=0.f;
    #pragma unroll
    for (int q=0;q<6;++q) av += accP[q*64+lane];
    float tv = ((totP[0]+totP[1])+(totP[2]+totP[3]))+(totP[4]+totP[5]);
    float rnew = __builtin_fmaf(av, fast_rcp(tv), tanh_fast(rtl));
    if (wv==0 && s==idx2) rn_keep = rnew;
    float rwp=0.f, rtp=0.f;
    #pragma unroll
    for (int jj=0;jj<11;++jj){
      if (jj<cnt){
        float rv = rdlane(rnew, k0+jj);
        rwp = __builtin_fmaf(rv, wrch[jj], rwp);
        rtp = __builtin_fmaf(rv, wtch[jj], rtp);
      }
    }
    rwrtP[wv*64+lane] = make_float2(rwp, rtp);
    __syncthreads();
  }
  if (wv==0) rn_cap[b*E + lane] = rn_keep;
}

// ---------------------------------------------------------------------------
// K4: final MLP. 64 blocks x 128 threads.
// ---------------------------------------------------------------------------
__global__ __launch_bounds__(128, 1) void final_kernel(
  const float* __restrict__ rn_cap, const float* __restrict__ hn_cap,
  const float* __restrict__ wp, const float* __restrict__ wx,
  const float* __restrict__ l1W, const float* __restrict__ l1b,
  const float* __restrict__ lW, const float* __restrict__ lb,
  float* __restrict__ out)
{
  const int b = blockIdx.x, t = threadIdx.x;
  __shared__ float rn[E], hn[E], hid1[E], hid2[128];
  if (t<E){ rn[t]=rn_cap[b*E+t]; hn[t]=hn_cap[b*E+t]; }
  __syncthreads();
  if (t<E){
    float a0=0,a1=0;
    #pragma unroll
    for (int k=0;k<E;++k){
      a0 += rn[k]*wp[k*E+t];
      a1 += hn[k]*wx[k*E+t];
    }
    hid1[t] = tanh_fast(a0+a1);
  }
  __syncthreads();
  {
    float acc = l1b[t];
    #pragma unroll
    for (int k=0;k<E;++k) acc += hid1[k]*l1W[t*E+k];
    hid2[t] = tanh_fast(acc);
  }
  __syncthreads();
  if (t<4){
    float acc = lb[t];
    #pragma unroll
    for (int k=0;k<128;++k) acc += hid2[k]*lW[t*128+k];
    out[b*4+t] = acc;
  }
}

extern "C" void kernel_launch(void* const* d_in, const int* in_sizes, int n_in,
                              void* d_out, int out_size, void* d_ws, size_t ws_size,
                              hipStream_t stream)
{
  const int*   sent1 = (const int*)  d_in[0];
  const int*   sent2 = (const int*)  d_in[1];
  const int*   s1len = (const int*)  d_in[2];
  const int*   s2len = (const int*)  d_in[3];
  const float* s1s   = (const float*)d_in[4];
  const float* emb   = (const float*)d_in[6];
  const float* Wih1  = (const float*)d_in[7];
  const float* Whh1  = (const float*)d_in[8];
  const float* bih1  = (const float*)d_in[9];
  const float* bhh1  = (const float*)d_in[10];
  const float* Wih2  = (const float*)d_in[11];
  const float* Whh2  = (const float*)d_in[12];
  const float* bih2  = (const float*)d_in[13];
  const float* bhh2  = (const float*)d_in[14];
  const float* wy    = (const float*)d_in[15];
  const float* wh    = (const float*)d_in[16];
  const float* w     = (const float*)d_in[17];
  const float* wp    = (const float*)d_in[18];
  const float* wx    = (const float*)d_in[19];
  const float* wr    = (const float*)d_in[20];
  const float* wt    = (const float*)d_in[21];
  const float* l1W   = (const float*)d_in[22];
  const float* l1b   = (const float*)d_in[23];
  const float* lW    = (const float*)d_in[24];
  const float* lb    = (const float*)d_in[25];
  float* out = (float*)d_out;

  float* ws  = (float*)d_ws;
  float* gx1 = ws;                         // 64*384*256 = 6291456 floats
  float* gx2 = gx1 + 6291456;
  float* h1  = gx2 + 6291456;              // 64*384*64 = 1572864
  float* outa= h1  + 1572864;
  float* Eg  = outa + 1572864;
  float* rnc = Eg  + 1572864;              // 4096
  float* hnc = rnc + 4096;

  hipLaunchKernelGGL(gx_kernel, dim3(512), dim3(256), 0, stream,
    sent1, sent2, emb, Wih1, bih1, bhh1, Wih2, bih2, bhh2, gx1, gx2);
  hipLaunchKernelGGL(lstm_kernel, dim3(64), dim3(256), 0, stream,
    gx1, gx2, Whh1, Whh2, s1len, s2len, h1, outa, hnc);
  hipLaunchKernelGGL(base_kernel, dim3(1536), dim3(256), 0, stream,
    h1, outa, wy, wh, Eg);
  hipLaunchKernelGGL(attn_kernel, dim3(64), dim3(384), 0, stream,
    h1, Eg, w, wr, wt, s1s, s2len, rnc);
  hipLaunchKernelGGL(final_kernel, dim3(64), dim3(128), 0, stream,
    rnc, hnc, wp, wx, l1W, l1b, lW, lb, out);
}